// Round 3
// baseline (558.508 us; speedup 1.0000x reference)
//
#include <hip/hip_runtime.h>

#define N_USERC 50000
#define N_ITEMC 100000
#define NN      150000      // total nodes
#define DD      64
#define NLAYER  3
#define NNZC    2400000
#define BB      4096
#define NRID    (3*BB)      // 12288 gathered output rows
#define NBKT    147         // ceil(NN/1024) row buckets (row>>10)
#define NABLK   586         // ceil(NNZC/4096) partition blocks
#define NTILE   4688        // ceil(NN/32) 32-row tiles for mfma dense
#define NDBLK   1172        // NTILE/4 blocks (4 waves/block, 1 tile/wave)

typedef unsigned short ushort_t;
typedef __attribute__((ext_vector_type(8))) short bf16x8;   // 8 bf16 = 4 VGPRs (A/B frag)
typedef __attribute__((ext_vector_type(4))) float f32x4;    // C/D frag

static __device__ __forceinline__ float bf2f(ushort_t b) {
    unsigned int u = ((unsigned int)b) << 16;
    return __uint_as_float(u);
}
static __device__ __forceinline__ ushort_t f2bf(float f) {
    unsigned int u = __float_as_uint(f);
    u = u + 0x7FFFu + ((u >> 16) & 1u);   // round-to-nearest-even
    return (ushort_t)(u >> 16);
}

// ---- dtype sniff: flag=1 if float inputs are packed bf16, 0 if fp32 ----
__global__ __launch_bounds__(64) void k_sniff(const unsigned int* __restrict__ ue_words,
                                              int* __restrict__ flag) {
    int lane = threadIdx.x;
    int cnt = 0;
    for (int i = 0; i < 4; i++) {
        unsigned int w = ue_words[lane * 4 + i];
        unsigned int lo = w & 0xFFFFu;
        unsigned int ex = (lo >> 7) & 0xFF;
        if (ex >= 100 && ex <= 132) cnt++;
    }
    for (int m = 1; m < 64; m <<= 1) cnt += __shfl_xor(cnt, m, 64);
    if (lane == 0) *flag = (cnt >= 128) ? 1 : 0;
}

// ---- init: E fp32 from inputs ----
__global__ __launch_bounds__(256) void k_init(const void* __restrict__ ue,
                                              const void* __restrict__ ie,
                                              const int* __restrict__ flag,
                                              float* __restrict__ E) {
    int idx = blockIdx.x * 256 + threadIdx.x;           // over NN*64
    if (idx >= NN * DD) return;
    int row = idx >> 6;
    bool isU = row < N_USERC;
    int si = isU ? idx : idx - N_USERC * DD;
    float v;
    if (*flag) {
        v = bf2f(isU ? ((const ushort_t*)ue)[si] : ((const ushort_t*)ie)[si]);
    } else {
        v = isU ? ((const float*)ue)[si] : ((const float*)ie)[si];
    }
    E[idx] = v;
}

// ---- E (fp32) -> Eb (bf16 gather copy); runs after phaseB (Eb aliases binned) ----
__global__ __launch_bounds__(256) void k_tobf(const float* __restrict__ E,
                                              ushort_t* __restrict__ Eb) {
    int idx = blockIdx.x * 256 + threadIdx.x;
    if (idx < NN * DD) Eb[idx] = f2bf(E[idx]);
}

// ---- W prep: pack W1,W2 into pre-swizzled bf16 B-fragments + bias sums ----
// Wfrag layout: [l][s(4)][jt(4)][lane(64)][i(8)] ushort.
// B-frag (16x16x32): col = jt*16 + (lane&15); k = 32*(s&1) + 8*(lane>>4) + i;
// matrix = W1 for s<2, W2 for s>=2. A-side uses the identical k map, so any
// HW k-permutation cancels (same map both operands).
__global__ __launch_bounds__(256) void k_wprep(const void* __restrict__ W1,
                                               const void* __restrict__ W2,
                                               const void* __restrict__ b1,
                                               const void* __restrict__ b2,
                                               const int* __restrict__ flag,
                                               ushort_t* __restrict__ Wfrag,
                                               float* __restrict__ bsum) {
    int idx = blockIdx.x * 256 + threadIdx.x;
    int isbf = *flag;
    if (idx < NLAYER * 4 * 4 * 64 * 8) {
        int i    = idx & 7;
        int lane = (idx >> 3) & 63;
        int jt   = (idx >> 9) & 3;
        int s    = (idx >> 11) & 3;
        int l    = idx >> 13;
        int kfull = 32 * (s & 1) + 8 * (lane >> 4) + i;
        int col   = jt * 16 + (lane & 15);
        const void* W = (s < 2) ? W1 : W2;
        size_t off = (size_t)l * 4096 + (size_t)kfull * 64 + col;
        float v = isbf ? bf2f(((const ushort_t*)W)[off]) : ((const float*)W)[off];
        Wfrag[idx] = f2bf(v);
    } else {
        int r = idx - NLAYER * 4 * 4 * 64 * 8;
        if (r < NLAYER * 64) {
            float v1 = isbf ? bf2f(((const ushort_t*)b1)[r]) : ((const float*)b1)[r];
            float v2 = isbf ? bf2f(((const ushort_t*)b2)[r]) : ((const float*)b2)[r];
            bsum[r] = v1 + v2;
        }
    }
}

// ---- zero the 147 bucket counters ----
__global__ __launch_bounds__(256) void k_zb(int* __restrict__ bucket_cnt) {
    if (threadIdx.x < NBKT) bucket_cnt[threadIdx.x] = 0;
}

// ---- bucket histogram: 147 buckets of 1024 rows ----
__global__ __launch_bounds__(256) void k_bhist(const int* __restrict__ rows,
                                               int* __restrict__ bucket_cnt) {
    __shared__ int h[NBKT];
    int t = threadIdx.x;
    if (t < NBKT) h[t] = 0;
    __syncthreads();
    int e0 = blockIdx.x * 4096;
#pragma unroll
    for (int i = 0; i < 16; i++) {
        int e = e0 + t + i * 256;
        if (e < NNZC) atomicAdd(&h[rows[e] >> 10], 1);
    }
    __syncthreads();
    if (t < NBKT && h[t]) atomicAdd(&bucket_cnt[t], h[t]);
}

// ---- exclusive scan of 147 bucket counts; seed bases/cursors ----
__global__ __launch_bounds__(256) void k_bscan(const int* __restrict__ bucket_cnt,
                                               int* __restrict__ gbase,
                                               int* __restrict__ gcursor,
                                               int* __restrict__ row_ptr) {
    __shared__ int s[256];
    int t = threadIdx.x;
    int v = (t < NBKT) ? bucket_cnt[t] : 0;
    s[t] = v; __syncthreads();
    for (int off = 1; off < 256; off <<= 1) {
        int x = (t >= off) ? s[t - off] : 0;
        __syncthreads();
        s[t] += x;
        __syncthreads();
    }
    if (t < NBKT) { int ex = s[t] - v; gbase[t] = ex; gcursor[t] = ex; }
    if (t == 0) { gbase[NBKT] = NNZC; row_ptr[NN] = NNZC; }
}

// ---- phase A: partition edges into 147 row-buckets ----
__global__ __launch_bounds__(256) void k_phaseA(const int* __restrict__ rows,
                                                const int* __restrict__ cols,
                                                const void* __restrict__ vals,
                                                const int* __restrict__ flag,
                                                int* __restrict__ gcursor,
                                                int2* __restrict__ binned) {
    __shared__ int hist[NBKT], base_[NBKT], lcur[NBKT];
    int t = threadIdx.x;
    int e0 = blockIdx.x * 4096;
    if (t < NBKT) { hist[t] = 0; lcur[t] = 0; }
    __syncthreads();
    int myrow[16];
#pragma unroll
    for (int i = 0; i < 16; i++) {
        int e = e0 + t + i * 256;
        int r = -1;
        if (e < NNZC) { r = rows[e]; atomicAdd(&hist[r >> 10], 1); }
        myrow[i] = r;
    }
    __syncthreads();
    if (t < NBKT && hist[t] > 0) base_[t] = atomicAdd(&gcursor[t], hist[t]);
    __syncthreads();
    int isbf = *flag;
#pragma unroll
    for (int i = 0; i < 16; i++) {
        int e = e0 + t + i * 256;
        if (e < NNZC) {
            int r = myrow[i];
            int bkt = r >> 10;
            int off = atomicAdd(&lcur[bkt], 1);
            int pos = base_[bkt] + off;
            int c = cols[e];
            float v = isbf ? bf2f(((const ushort_t*)vals)[e]) : ((const float*)vals)[e];
            binned[pos] = make_int2(((r & 1023) << 18) | c, __float_as_int(v));
        }
    }
}

// ---- phase B: one block per bucket; exact CSR slice via LDS hist+scan+cursor ----
__global__ __launch_bounds__(256) void k_phaseB(const int* __restrict__ gbase,
                                                const int2* __restrict__ binned,
                                                int2* __restrict__ ep,
                                                int* __restrict__ row_ptr) {
    __shared__ int rc[1024];
    __shared__ int rofs[1024];
    int b = blockIdx.x, t = threadIdx.x;
    int s = gbase[b], e = gbase[b + 1];
    for (int i = t; i < 1024; i += 256) rc[i] = 0;
    __syncthreads();
    for (int i = s + t; i < e; i += 256)
        atomicAdd(&rc[binned[i].x >> 18], 1);
    __syncthreads();
    for (int i = t; i < 1024; i += 256) rofs[i] = rc[i];
    __syncthreads();
    for (int off = 1; off < 1024; off <<= 1) {
        int v[4];
#pragma unroll
        for (int j = 0; j < 4; j++) {
            int idx = t + j * 256;
            v[j] = (idx >= off) ? rc[idx - off] : 0;
        }
        __syncthreads();
#pragma unroll
        for (int j = 0; j < 4; j++) rc[t + j * 256] += v[j];
        __syncthreads();
    }
    for (int i = t; i < 1024; i += 256) {
        int ex = rc[i] - rofs[i];
        int gr = b * 1024 + i;
        if (gr < NN) row_ptr[gr] = s + ex;
        rofs[i] = ex;
    }
    __syncthreads();
    for (int i = s + t; i < e; i += 256) {
        int2 en = binned[i];
        int rl = en.x >> 18;
        int c  = en.x & 0x3FFFF;
        int off = atomicAdd(&rofs[rl], 1);
        ep[s + off] = make_int2(c, en.y);
    }
}

// ---- SpMM v5: lane = (half = edge-of-pair, dp = dim-pair). Per 16-edge chunk:
// 8 independent ep pair-loads (each 16B, 1 line) then 8 independent gathers
// (each 2 rows x 128B, fully coalesced: 32 lanes x 4B). Each lane holds only
// 2 accumulators -> fold is ONE xor32 stage x 2 values (24 DS ops -> 2 vs v3's
// 3-stage butterfly), and unpack+FMA per edge-dim halves. Store: one coalesced
// float2 per low-half lane. ----
__global__ __launch_bounds__(256) void k_spmm(const int* __restrict__ row_ptr,
                                              const int2* __restrict__ ep,
                                              const ushort_t* __restrict__ Eb,
                                              float* __restrict__ LE) {
    int wv = threadIdx.x >> 6;
    int r = blockIdx.x * 4 + wv;               // 37500*4 = 150000 exact
    int lane = threadIdx.x & 63;
    int half = lane >> 5;                      // which edge of the pair
    int dp   = lane & 31;                      // dim pair: dims 2dp, 2dp+1
    int s = __builtin_amdgcn_readfirstlane(row_ptr[r]);
    int e = __builtin_amdgcn_readfirstlane(row_ptr[r + 1]);
    float a0 = 0.f, a1 = 0.f;

    for (int i = s; i < e; i += 16) {
        // stage 1: 8 ep pair-loads (independent; 2 consecutive int2 per instr)
        int2 pv[8];
#pragma unroll
        for (int g = 0; g < 8; g++) {
            int idx = i + 2 * g + half;
            int j = (idx < e) ? idx : s;
            pv[g] = ep[j];
        }
        // stage 2: 8 gathers (each depends only on its pv; all go in flight)
        unsigned int q[8];
#pragma unroll
        for (int g = 0; g < 8; g++) {
            q[g] = *(const unsigned int*)(Eb + ((size_t)(unsigned)pv[g].x << 6) + dp * 2);
        }
        // stage 3: unpack + FMA (1 unpack + 1 FMA per edge-dim)
#pragma unroll
        for (int g = 0; g < 8; g++) {
            int idx = i + 2 * g + half;
            float w = (idx < e) ? __int_as_float(pv[g].y) : 0.f;
            a0 = fmaf(w, __uint_as_float(q[g] << 16),          a0);
            a1 = fmaf(w, __uint_as_float(q[g] & 0xffff0000u),  a1);
        }
    }
    // fold: single cross-half stage
    a0 += __shfl_xor(a0, 32, 64);
    a1 += __shfl_xor(a1, 32, 64);
    if (lane < 32) {
        float2* dst = (float2*)(LE + (size_t)r * DD + dp * 2);
        *dst = make_float2(a0, a1);
    }
}

// ---- dense v3: MFMA. H = [x1|x2] @ [W1;W2] with split-precision bf16 A-frags.
// One wave = 32 rows x 64 cols; 2 row-tiles x 4 col-tiles of 16x16x32 mfma.
// A-frag: row = lane&15, k = 32*(s&1) + 8*(lane>>4) + i  (same k map as wprep's
// B-frags, so HW k-permutation cancels). x split hi+lo: x-rounding error ~2^-16,
// only W bf16 rounding remains (exact if inputs are bf16).
// C/D layout (HW-verified): col = lane&15, row = (lane>>4)*4 + reg. ----
__global__ __launch_bounds__(256) void k_mdense(const float* __restrict__ LE,
                                                float* __restrict__ E,
                                                ushort_t* __restrict__ Eb,
                                                const ushort_t* __restrict__ Wfrag,
                                                const float* __restrict__ bsum,
                                                int layer) {
    int lane = threadIdx.x & 63;
    int tile = (blockIdx.x << 2) + (threadIdx.x >> 6);   // 0..NTILE-1
    int hl  = lane >> 4;
    int l16 = lane & 15;
    int r0 = tile << 5;

    // B-fragments: 16 x bf16x8 = 64 VGPRs, loaded once (coalesced dwordx4)
    bf16x8 wf[4][4];
    const uint4* wb = (const uint4*)(Wfrag + (size_t)layer * 8192);
#pragma unroll
    for (int s = 0; s < 4; s++)
#pragma unroll
        for (int jt = 0; jt < 4; jt++) {
            uint4 q = wb[(s * 4 + jt) * 64 + lane];
            __builtin_memcpy(&wf[s][jt], &q, 16);
        }
    float bs[4];
#pragma unroll
    for (int jt = 0; jt < 4; jt++) bs[jt] = bsum[layer * 64 + jt * 16 + l16];

    f32x4 acc[2][4];
#pragma unroll
    for (int rt = 0; rt < 2; rt++)
#pragma unroll
        for (int jt = 0; jt < 4; jt++) acc[rt][jt] = (f32x4){0.f, 0.f, 0.f, 0.f};

#pragma unroll
    for (int rt = 0; rt < 2; rt++) {
        int row = r0 + rt * 16 + l16;
        int rr = (row < NN) ? row : (NN - 1);            // clamp tail reads
        bf16x8 a1h[2], a1l[2], a2h[2], a2l[2];
#pragma unroll
        for (int sh = 0; sh < 2; sh++) {
            const float4* lp = (const float4*)(LE + (size_t)rr * DD + sh * 32 + hl * 8);
            const float4* ev = (const float4*)(E  + (size_t)rr * DD + sh * 32 + hl * 8);
            float4 l0 = lp[0], l1 = lp[1];
            float4 e0 = ev[0], e1 = ev[1];
            float le[8] = {l0.x, l0.y, l0.z, l0.w, l1.x, l1.y, l1.z, l1.w};
            float ee[8] = {e0.x, e0.y, e0.z, e0.w, e1.x, e1.y, e1.z, e1.w};
            unsigned int u1h[4], u1l[4], u2h[4], u2l[4];
#pragma unroll
            for (int d = 0; d < 4; d++) {
                float s0 = le[2*d]   + ee[2*d];
                float s1 = le[2*d+1] + ee[2*d+1];
                float m0 = le[2*d]   * ee[2*d];
                float m1 = le[2*d+1] * ee[2*d+1];
                asm("v_cvt_pk_bf16_f32 %0, %1, %2" : "=v"(u1h[d]) : "v"(s0), "v"(s1));
                asm("v_cvt_pk_bf16_f32 %0, %1, %2" : "=v"(u2h[d]) : "v"(m0), "v"(m1));
                float s0r = s0 - __uint_as_float(u1h[d] << 16);
                float s1r = s1 - __uint_as_float(u1h[d] & 0xffff0000u);
                float m0r = m0 - __uint_as_float(u2h[d] << 16);
                float m1r = m1 - __uint_as_float(u2h[d] & 0xffff0000u);
                asm("v_cvt_pk_bf16_f32 %0, %1, %2" : "=v"(u1l[d]) : "v"(s0r), "v"(s1r));
                asm("v_cvt_pk_bf16_f32 %0, %1, %2" : "=v"(u2l[d]) : "v"(m0r), "v"(m1r));
            }
            __builtin_memcpy(&a1h[sh], u1h, 16);
            __builtin_memcpy(&a1l[sh], u1l, 16);
            __builtin_memcpy(&a2h[sh], u2h, 16);
            __builtin_memcpy(&a2l[sh], u2l, 16);
        }
#pragma unroll
        for (int jt = 0; jt < 4; jt++) {
            f32x4 a = acc[rt][jt];
            a = __builtin_amdgcn_mfma_f32_16x16x32_bf16(a1h[0], wf[0][jt], a, 0, 0, 0);
            a = __builtin_amdgcn_mfma_f32_16x16x32_bf16(a1l[0], wf[0][jt], a, 0, 0, 0);
            a = __builtin_amdgcn_mfma_f32_16x16x32_bf16(a1h[1], wf[1][jt], a, 0, 0, 0);
            a = __builtin_amdgcn_mfma_f32_16x16x32_bf16(a1l[1], wf[1][jt], a, 0, 0, 0);
            a = __builtin_amdgcn_mfma_f32_16x16x32_bf16(a2h[0], wf[2][jt], a, 0, 0, 0);
            a = __builtin_amdgcn_mfma_f32_16x16x32_bf16(a2l[0], wf[2][jt], a, 0, 0, 0);
            a = __builtin_amdgcn_mfma_f32_16x16x32_bf16(a2h[1], wf[3][jt], a, 0, 0, 0);
            a = __builtin_amdgcn_mfma_f32_16x16x32_bf16(a2l[1], wf[3][jt], a, 0, 0, 0);
            acc[rt][jt] = a;
        }
    }

#pragma unroll
    for (int rt = 0; rt < 2; rt++)
#pragma unroll
        for (int jt = 0; jt < 4; jt++) {
            int col = jt * 16 + l16;
#pragma unroll
            for (int g = 0; g < 4; g++) {
                int r = r0 + rt * 16 + hl * 4 + g;
                float h = acc[rt][jt][g] + bs[jt];
                h = (h >= 0.f) ? h : 0.2f * h;
                if (r < NN) {
                    E[(size_t)r * DD + col]  = h;
                    Eb[(size_t)r * DD + col] = f2bf(h);
                }
            }
        }
}

static __device__ __forceinline__ int rid_to_node(int rid,
                                                  const int* users, const int* pos, const int* neg) {
    if (rid < BB)      return users[rid] - 1;
    if (rid < 2 * BB)  return N_USERC + pos[rid - BB] - 1;
    return N_USERC + neg[rid - 2 * BB] - 1;
}

// ---- slice 0 of output: raw initial embedding (fp32) of gathered rows ----
__global__ __launch_bounds__(256) void k_outslice0(const float* __restrict__ E,
                                                   const int* __restrict__ users,
                                                   const int* __restrict__ pos,
                                                   const int* __restrict__ neg,
                                                   float* __restrict__ out) {
    int rid  = blockIdx.x * 4 + (threadIdx.x >> 6);
    int lane = threadIdx.x & 63;
    if (rid >= NRID) return;
    int node = rid_to_node(rid, users, pos, neg);
    out[(size_t)rid * 256 + lane] = E[(size_t)node * DD + lane];
}

// ---- slice l+1: normalized current E of gathered rows (fp32) ----
__global__ __launch_bounds__(256) void k_outnorm(const float* __restrict__ E,
                                                 const int* __restrict__ users,
                                                 const int* __restrict__ pos,
                                                 const int* __restrict__ neg,
                                                 float* __restrict__ out,
                                                 int cbase) {
    int rid  = blockIdx.x * 4 + (threadIdx.x >> 6);
    int lane = threadIdx.x & 63;
    if (rid >= NRID) return;
    int node = rid_to_node(rid, users, pos, neg);
    float v = E[(size_t)node * DD + lane];
    float p2 = v * v;
    for (int m = 1; m < 64; m <<= 1) p2 += __shfl_xor(p2, m, 64);
    float nr = fmaxf(sqrtf(p2), 1e-12f);
    out[(size_t)rid * 256 + cbase + lane] = v / nr;
}

extern "C" void kernel_launch(void* const* d_in, const int* in_sizes, int n_in,
                              void* d_out, int out_size, void* d_ws, size_t ws_size,
                              hipStream_t stream) {
    const void* ue   = d_in[0];
    const void* ie   = d_in[1];
    const void* ev   = d_in[2];
    const void* W1   = d_in[3];
    const void* b1   = d_in[4];
    const void* W2   = d_in[5];
    const void* b2   = d_in[6];
    const int*  ei   = (const int*)d_in[7];
    const int*  usr  = (const int*)d_in[8];
    const int*  posi = (const int*)d_in[9];
    const int*  negi = (const int*)d_in[10];
    float*      out  = (float*)d_out;

    const int* rows = ei;
    const int* cols = ei + NNZC;

    // workspace carve — ~116 MB (Eb aliases binned: binned is dead after phaseB)
    char* w = (char*)d_ws;
    float*  E         = (float*)w;  w += (size_t)NN * DD * 4;    // 38.4 MB
    float*  LE        = (float*)w;  w += (size_t)NN * DD * 4;    // 38.4 MB
    int2*   binned    = (int2*)w;   w += (size_t)NNZC * 8;       // 19.2 MB
    ushort_t* Eb      = (ushort_t*)binned;                       // alias (19.2 MB need)
    int2*   ep        = (int2*)w;   w += (size_t)NNZC * 8;       // 19.2 MB
    int*    row_ptr   = (int*)w;    w += 600320;                 // NN+1 ints padded
    int*    gbase     = (int*)w;    w += 1024;
    int*    gcursor   = (int*)w;    w += 1024;
    int*    bucket_cnt= (int*)w;    w += 1024;
    int*    flag      = (int*)w;    w += 256;
    ushort_t* Wfrag   = (ushort_t*)w; w += 49152;                // 3*4*4*64*8 bf16
    float*  bsum      = (float*)w;  w += 768;                    // 3*64 fp32

    k_sniff<<<1, 64, 0, stream>>>((const unsigned int*)ue, flag);
    k_wprep<<<97, 256, 0, stream>>>(W1, W2, b1, b2, flag, Wfrag, bsum);
    k_init<<<37500, 256, 0, stream>>>(ue, ie, flag, E);
    k_zb<<<1, 256, 0, stream>>>(bucket_cnt);
    k_bhist<<<NABLK, 256, 0, stream>>>(rows, bucket_cnt);
    k_bscan<<<1, 256, 0, stream>>>(bucket_cnt, gbase, gcursor, row_ptr);
    k_phaseA<<<NABLK, 256, 0, stream>>>(rows, cols, ev, flag, gcursor, binned);
    k_phaseB<<<NBKT, 256, 0, stream>>>(gbase, binned, ep, row_ptr);
    k_tobf<<<37500, 256, 0, stream>>>(E, Eb);      // after phaseB: binned is dead

    k_outslice0<<<3072, 256, 0, stream>>>(E, usr, posi, negi, out);

    for (int l = 0; l < NLAYER; l++) {
        k_spmm<<<37500, 256, 0, stream>>>(row_ptr, ep, Eb, LE);
        k_mdense<<<NDBLK, 256, 0, stream>>>(LE, E, Eb, Wfrag, bsum, l);
        k_outnorm<<<3072, 256, 0, stream>>>(E, usr, posi, negi, out, 64 * (l + 1));
    }
}

// Round 4
// 527.435 us; speedup vs baseline: 1.0589x; 1.0589x over previous
//
#include <hip/hip_runtime.h>

#define N_USERC 50000
#define N_ITEMC 100000
#define NN      150000      // total nodes
#define DD      64
#define NLAYER  3
#define NNZC    2400000
#define BB      4096
#define NRID    (3*BB)      // 12288 gathered output rows
#define NBKT    147         // ceil(NN/1024) row buckets (row>>10)
#define NABLK   586         // ceil(NNZC/4096) partition blocks
#define NTILE   4688        // ceil(NN/32) 32-row tiles (fused layer kernel)

typedef unsigned short ushort_t;
typedef __attribute__((ext_vector_type(8))) short bf16x8;   // 8 bf16 = 4 VGPRs (A/B frag)
typedef __attribute__((ext_vector_type(4))) float f32x4;    // C/D frag

static __device__ __forceinline__ float bf2f(ushort_t b) {
    unsigned int u = ((unsigned int)b) << 16;
    return __uint_as_float(u);
}
static __device__ __forceinline__ ushort_t f2bf(float f) {
    unsigned int u = __float_as_uint(f);
    u = u + 0x7FFFu + ((u >> 16) & 1u);   // round-to-nearest-even
    return (ushort_t)(u >> 16);
}

// ---- dtype sniff (flag=1 if inputs are packed bf16) + zero bucket counters ----
__global__ __launch_bounds__(256) void k_sniffzb(const unsigned int* __restrict__ ue_words,
                                                 int* __restrict__ flag,
                                                 int* __restrict__ bucket_cnt) {
    int t = threadIdx.x;
    if (t < 64) {
        int cnt = 0;
        for (int i = 0; i < 4; i++) {
            unsigned int w = ue_words[t * 4 + i];
            unsigned int lo = w & 0xFFFFu;
            unsigned int ex = (lo >> 7) & 0xFF;
            if (ex >= 100 && ex <= 132) cnt++;
        }
        for (int m = 1; m < 64; m <<= 1) cnt += __shfl_xor(cnt, m, 64);
        if (t == 0) *flag = (cnt >= 128) ? 1 : 0;
    } else if (t - 64 < NBKT) {
        bucket_cnt[t - 64] = 0;
    }
}

// ---- init2: E fp32 + Eb bf16 from inputs (runs after phaseB: Eb0 aliases binned) ----
__global__ __launch_bounds__(256) void k_init2(const void* __restrict__ ue,
                                               const void* __restrict__ ie,
                                               const int* __restrict__ flag,
                                               float* __restrict__ E,
                                               ushort_t* __restrict__ Eb0) {
    int idx = blockIdx.x * 256 + threadIdx.x;           // over NN*64
    if (idx >= NN * DD) return;
    int row = idx >> 6;
    bool isU = row < N_USERC;
    int si = isU ? idx : idx - N_USERC * DD;
    float v;
    if (*flag) {
        v = bf2f(isU ? ((const ushort_t*)ue)[si] : ((const ushort_t*)ie)[si]);
    } else {
        v = isU ? ((const float*)ue)[si] : ((const float*)ie)[si];
    }
    E[idx] = v;
    Eb0[idx] = f2bf(v);
}

// ---- W prep: pack W1,W2 into pre-swizzled bf16 B-fragments + bias sums ----
// Wfrag layout: [l][s(4)][jt(4)][lane(64)][i(8)] ushort.
// B-frag (16x16x32): col = jt*16 + (lane&15); k = 32*(s&1) + 8*(lane>>4) + i;
// matrix = W1 for s<2, W2 for s>=2. A-side uses the identical k map, so any
// HW k-permutation cancels (same map both operands).
__global__ __launch_bounds__(256) void k_wprep(const void* __restrict__ W1,
                                               const void* __restrict__ W2,
                                               const void* __restrict__ b1,
                                               const void* __restrict__ b2,
                                               const int* __restrict__ flag,
                                               ushort_t* __restrict__ Wfrag,
                                               float* __restrict__ bsum) {
    int idx = blockIdx.x * 256 + threadIdx.x;
    int isbf = *flag;
    if (idx < NLAYER * 4 * 4 * 64 * 8) {
        int i    = idx & 7;
        int lane = (idx >> 3) & 63;
        int jt   = (idx >> 9) & 3;
        int s    = (idx >> 11) & 3;
        int l    = idx >> 13;
        int kfull = 32 * (s & 1) + 8 * (lane >> 4) + i;
        int col   = jt * 16 + (lane & 15);
        const void* W = (s < 2) ? W1 : W2;
        size_t off = (size_t)l * 4096 + (size_t)kfull * 64 + col;
        float v = isbf ? bf2f(((const ushort_t*)W)[off]) : ((const float*)W)[off];
        Wfrag[idx] = f2bf(v);
    } else {
        int r = idx - NLAYER * 4 * 4 * 64 * 8;
        if (r < NLAYER * 64) {
            float v1 = isbf ? bf2f(((const ushort_t*)b1)[r]) : ((const float*)b1)[r];
            float v2 = isbf ? bf2f(((const ushort_t*)b2)[r]) : ((const float*)b2)[r];
            bsum[r] = v1 + v2;
        }
    }
}

// ---- bucket histogram: 147 buckets of 1024 rows ----
__global__ __launch_bounds__(256) void k_bhist(const int* __restrict__ rows,
                                               int* __restrict__ bucket_cnt) {
    __shared__ int h[NBKT];
    int t = threadIdx.x;
    if (t < NBKT) h[t] = 0;
    __syncthreads();
    int e0 = blockIdx.x * 4096;
#pragma unroll
    for (int i = 0; i < 16; i++) {
        int e = e0 + t + i * 256;
        if (e < NNZC) atomicAdd(&h[rows[e] >> 10], 1);
    }
    __syncthreads();
    if (t < NBKT && h[t]) atomicAdd(&bucket_cnt[t], h[t]);
}

// ---- exclusive scan of 147 bucket counts; seed bases/cursors ----
__global__ __launch_bounds__(256) void k_bscan(const int* __restrict__ bucket_cnt,
                                               int* __restrict__ gbase,
                                               int* __restrict__ gcursor,
                                               int* __restrict__ row_ptr) {
    __shared__ int s[256];
    int t = threadIdx.x;
    int v = (t < NBKT) ? bucket_cnt[t] : 0;
    s[t] = v; __syncthreads();
    for (int off = 1; off < 256; off <<= 1) {
        int x = (t >= off) ? s[t - off] : 0;
        __syncthreads();
        s[t] += x;
        __syncthreads();
    }
    if (t < NBKT) { int ex = s[t] - v; gbase[t] = ex; gcursor[t] = ex; }
    if (t == 0) { gbase[NBKT] = NNZC; row_ptr[NN] = NNZC; }
}

// ---- phase A: partition edges into 147 row-buckets ----
__global__ __launch_bounds__(256) void k_phaseA(const int* __restrict__ rows,
                                                const int* __restrict__ cols,
                                                const void* __restrict__ vals,
                                                const int* __restrict__ flag,
                                                int* __restrict__ gcursor,
                                                int2* __restrict__ binned) {
    __shared__ int hist[NBKT], base_[NBKT], lcur[NBKT];
    int t = threadIdx.x;
    int e0 = blockIdx.x * 4096;
    if (t < NBKT) { hist[t] = 0; lcur[t] = 0; }
    __syncthreads();
    int myrow[16];
#pragma unroll
    for (int i = 0; i < 16; i++) {
        int e = e0 + t + i * 256;
        int r = -1;
        if (e < NNZC) { r = rows[e]; atomicAdd(&hist[r >> 10], 1); }
        myrow[i] = r;
    }
    __syncthreads();
    if (t < NBKT && hist[t] > 0) base_[t] = atomicAdd(&gcursor[t], hist[t]);
    __syncthreads();
    int isbf = *flag;
#pragma unroll
    for (int i = 0; i < 16; i++) {
        int e = e0 + t + i * 256;
        if (e < NNZC) {
            int r = myrow[i];
            int bkt = r >> 10;
            int off = atomicAdd(&lcur[bkt], 1);
            int pos = base_[bkt] + off;
            int c = cols[e];
            float v = isbf ? bf2f(((const ushort_t*)vals)[e]) : ((const float*)vals)[e];
            binned[pos] = make_int2(((r & 1023) << 18) | c, __float_as_int(v));
        }
    }
}

// ---- phase B: one block per bucket; exact CSR slice via LDS hist+scan+cursor ----
__global__ __launch_bounds__(256) void k_phaseB(const int* __restrict__ gbase,
                                                const int2* __restrict__ binned,
                                                int2* __restrict__ ep,
                                                int* __restrict__ row_ptr) {
    __shared__ int rc[1024];
    __shared__ int rofs[1024];
    int b = blockIdx.x, t = threadIdx.x;
    int s = gbase[b], e = gbase[b + 1];
    for (int i = t; i < 1024; i += 256) rc[i] = 0;
    __syncthreads();
    for (int i = s + t; i < e; i += 256)
        atomicAdd(&rc[binned[i].x >> 18], 1);
    __syncthreads();
    for (int i = t; i < 1024; i += 256) rofs[i] = rc[i];
    __syncthreads();
    for (int off = 1; off < 1024; off <<= 1) {
        int v[4];
#pragma unroll
        for (int j = 0; j < 4; j++) {
            int idx = t + j * 256;
            v[j] = (idx >= off) ? rc[idx - off] : 0;
        }
        __syncthreads();
#pragma unroll
        for (int j = 0; j < 4; j++) rc[t + j * 256] += v[j];
        __syncthreads();
    }
    for (int i = t; i < 1024; i += 256) {
        int ex = rc[i] - rofs[i];
        int gr = b * 1024 + i;
        if (gr < NN) row_ptr[gr] = s + ex;
        rofs[i] = ex;
    }
    __syncthreads();
    for (int i = s + t; i < e; i += 256) {
        int2 en = binned[i];
        int rl = en.x >> 18;
        int c  = en.x & 0x3FFFF;
        int off = atomicAdd(&rofs[rl], 1);
        ep[s + off] = make_int2(c, en.y);
    }
}

// ---- fused layer: block = 32 rows. Phase 1: stage E rows in LDS (issued
// first, hides under gathers) + v3-shape spmm per row (wave = 1 row,
// oct=edge-slot, d8=8 dims, uint4 gathers) writing LE to LDS. Barrier.
// Phase 2: mdense MFMA tile reading x1/x2 from LDS (LE never touches HBM:
// -75 MB/layer). Eb is ping-pong buffered (Eb_in read-only this layer,
// Eb_out written) -> no cross-block race. E is read/written block-locally.
// LDS pad 68 floats/row: phase-2 16-lane row-reads spread 4*row%32 banks
// (2-way = free), and rows stay 16B-aligned for b128. ----
__global__ __launch_bounds__(256) void k_layer(const int* __restrict__ row_ptr,
                                               const int2* __restrict__ ep,
                                               const ushort_t* __restrict__ Eb_in,
                                               float* __restrict__ E,
                                               ushort_t* __restrict__ Eb_out,
                                               const ushort_t* __restrict__ Wfrag,
                                               const float* __restrict__ bsum,
                                               int layer) {
    __shared__ float sLE[32][68];
    __shared__ float sE [32][68];

    int t    = threadIdx.x;
    int wv   = t >> 6;
    int lane = t & 63;
    int oct  = lane >> 3;
    int d8   = (lane & 7) * 8;
    int hl   = lane >> 4;
    int l16  = lane & 15;
    int r0   = blockIdx.x << 5;

    // ---- E-row prefetch into LDS (overlaps with spmm gathers below) ----
    {
        int lr = t >> 3;
        int dm = (t & 7) * 8;
        int gr = r0 + lr;
        float4 va = make_float4(0.f, 0.f, 0.f, 0.f), vb = va;
        if (gr < NN) {
            const float4* p = (const float4*)(E + (size_t)gr * DD + dm);
            va = p[0]; vb = p[1];
        }
        *(float4*)&sE[lr][dm]     = va;
        *(float4*)&sE[lr][dm + 4] = vb;
    }

    // ---- phase 1: spmm, 8 rows per wave (v3 inner loop), LE -> LDS ----
    for (int sub = 0; sub < 8; sub++) {
        int lrow = sub * 4 + wv;
        int r = r0 + lrow;
        int s = 0, e = 0;
        if (r < NN) {
            s = __builtin_amdgcn_readfirstlane(row_ptr[r]);
            e = __builtin_amdgcn_readfirstlane(row_ptr[r + 1]);
        }
        float acc[8];
#pragma unroll
        for (int k = 0; k < 8; k++) acc[k] = 0.f;
        for (int i = s; i < e; i += 16) {
#pragma unroll
            for (int v = 0; v < 2; v++) {
                int idx = i + v * 8 + oct;
                bool valid = idx < e;
                int j = valid ? idx : s;
                int2 pv = ep[j];
                float w = valid ? __int_as_float(pv.y) : 0.f;
                uint4 q = *(const uint4*)(Eb_in + ((size_t)(unsigned)pv.x << 6) + d8);
                acc[0] = fmaf(w, __uint_as_float(q.x << 16),          acc[0]);
                acc[1] = fmaf(w, __uint_as_float(q.x & 0xffff0000u),  acc[1]);
                acc[2] = fmaf(w, __uint_as_float(q.y << 16),          acc[2]);
                acc[3] = fmaf(w, __uint_as_float(q.y & 0xffff0000u),  acc[3]);
                acc[4] = fmaf(w, __uint_as_float(q.z << 16),          acc[4]);
                acc[5] = fmaf(w, __uint_as_float(q.z & 0xffff0000u),  acc[5]);
                acc[6] = fmaf(w, __uint_as_float(q.w << 16),          acc[6]);
                acc[7] = fmaf(w, __uint_as_float(q.w & 0xffff0000u),  acc[7]);
            }
        }
#pragma unroll
        for (int m = 8; m < 64; m <<= 1)
#pragma unroll
            for (int k = 0; k < 8; k++) acc[k] += __shfl_xor(acc[k], m, 64);
        if (oct == 0) {
            *(float4*)&sLE[lrow][d8]     = make_float4(acc[0], acc[1], acc[2], acc[3]);
            *(float4*)&sLE[lrow][d8 + 4] = make_float4(acc[4], acc[5], acc[6], acc[7]);
        }
    }
    __syncthreads();

    // ---- phase 2: dense. wave -> (rt = wv&1, jts = {2*(wv>>1), 2*(wv>>1)+1}) ----
    int rt = wv & 1;
    int j0 = wv >> 1;                       // jt pair index
    int jtA = 2 * j0, jtB = 2 * j0 + 1;
    const uint4* wb = (const uint4*)(Wfrag + (size_t)layer * 8192);
    float bsA = bsum[layer * 64 + jtA * 16 + l16];
    float bsB = bsum[layer * 64 + jtB * 16 + l16];

    f32x4 accA = (f32x4){0.f, 0.f, 0.f, 0.f};
    f32x4 accB = (f32x4){0.f, 0.f, 0.f, 0.f};
    int lrow = rt * 16 + l16;

#pragma unroll
    for (int sh = 0; sh < 2; sh++) {
        // B-frags for this k-half: s=sh (x1), s=2+sh (x2), both jts
        bf16x8 w1a, w1b, w2a, w2b;
        {
            uint4 qa = wb[(sh * 4 + jtA) * 64 + lane];
            uint4 qb = wb[(sh * 4 + jtB) * 64 + lane];
            uint4 qc = wb[((2 + sh) * 4 + jtA) * 64 + lane];
            uint4 qd = wb[((2 + sh) * 4 + jtB) * 64 + lane];
            __builtin_memcpy(&w1a, &qa, 16);
            __builtin_memcpy(&w1b, &qb, 16);
            __builtin_memcpy(&w2a, &qc, 16);
            __builtin_memcpy(&w2b, &qd, 16);
        }
        // A-frags (split precision hi+lo) from LDS
        const float* pl = &sLE[lrow][sh * 32 + hl * 8];
        const float* pe = &sE [lrow][sh * 32 + hl * 8];
        float4 l0 = *(const float4*)pl, l1 = *(const float4*)(pl + 4);
        float4 e0 = *(const float4*)pe, e1 = *(const float4*)(pe + 4);
        float le[8] = {l0.x, l0.y, l0.z, l0.w, l1.x, l1.y, l1.z, l1.w};
        float ee[8] = {e0.x, e0.y, e0.z, e0.w, e1.x, e1.y, e1.z, e1.w};
        unsigned int u1h[4], u1l[4], u2h[4], u2l[4];
#pragma unroll
        for (int d = 0; d < 4; d++) {
            float s0 = le[2*d]   + ee[2*d];
            float s1 = le[2*d+1] + ee[2*d+1];
            float m0 = le[2*d]   * ee[2*d];
            float m1 = le[2*d+1] * ee[2*d+1];
            asm("v_cvt_pk_bf16_f32 %0, %1, %2" : "=v"(u1h[d]) : "v"(s0), "v"(s1));
            asm("v_cvt_pk_bf16_f32 %0, %1, %2" : "=v"(u2h[d]) : "v"(m0), "v"(m1));
            float s0r = s0 - __uint_as_float(u1h[d] << 16);
            float s1r = s1 - __uint_as_float(u1h[d] & 0xffff0000u);
            float m0r = m0 - __uint_as_float(u2h[d] << 16);
            float m1r = m1 - __uint_as_float(u2h[d] & 0xffff0000u);
            asm("v_cvt_pk_bf16_f32 %0, %1, %2" : "=v"(u1l[d]) : "v"(s0r), "v"(s1r));
            asm("v_cvt_pk_bf16_f32 %0, %1, %2" : "=v"(u2l[d]) : "v"(m0r), "v"(m1r));
        }
        bf16x8 p1h, p1l, p2h, p2l;
        __builtin_memcpy(&p1h, u1h, 16);
        __builtin_memcpy(&p1l, u1l, 16);
        __builtin_memcpy(&p2h, u2h, 16);
        __builtin_memcpy(&p2l, u2l, 16);

        accA = __builtin_amdgcn_mfma_f32_16x16x32_bf16(p1h, w1a, accA, 0, 0, 0);
        accA = __builtin_amdgcn_mfma_f32_16x16x32_bf16(p1l, w1a, accA, 0, 0, 0);
        accA = __builtin_amdgcn_mfma_f32_16x16x32_bf16(p2h, w2a, accA, 0, 0, 0);
        accA = __builtin_amdgcn_mfma_f32_16x16x32_bf16(p2l, w2a, accA, 0, 0, 0);
        accB = __builtin_amdgcn_mfma_f32_16x16x32_bf16(p1h, w1b, accB, 0, 0, 0);
        accB = __builtin_amdgcn_mfma_f32_16x16x32_bf16(p1l, w1b, accB, 0, 0, 0);
        accB = __builtin_amdgcn_mfma_f32_16x16x32_bf16(p2h, w2b, accB, 0, 0, 0);
        accB = __builtin_amdgcn_mfma_f32_16x16x32_bf16(p2l, w2b, accB, 0, 0, 0);
    }

    // epilogue: bias + leaky relu; C/D layout col=lane&15, row=(lane>>4)*4+g
#pragma unroll
    for (int g = 0; g < 4; g++) {
        int r = r0 + rt * 16 + hl * 4 + g;
        if (r < NN) {
            float hA = accA[g] + bsA; hA = (hA >= 0.f) ? hA : 0.2f * hA;
            float hB = accB[g] + bsB; hB = (hB >= 0.f) ? hB : 0.2f * hB;
            E[(size_t)r * DD + jtA * 16 + l16] = hA;
            E[(size_t)r * DD + jtB * 16 + l16] = hB;
            Eb_out[(size_t)r * DD + jtA * 16 + l16] = f2bf(hA);
            Eb_out[(size_t)r * DD + jtB * 16 + l16] = f2bf(hB);
        }
    }
}

static __device__ __forceinline__ int rid_to_node(int rid,
                                                  const int* users, const int* pos, const int* neg) {
    if (rid < BB)      return users[rid] - 1;
    if (rid < 2 * BB)  return N_USERC + pos[rid - BB] - 1;
    return N_USERC + neg[rid - 2 * BB] - 1;
}

// ---- slice 0 of output: raw initial embedding (fp32) of gathered rows ----
__global__ __launch_bounds__(256) void k_outslice0(const float* __restrict__ E,
                                                   const int* __restrict__ users,
                                                   const int* __restrict__ pos,
                                                   const int* __restrict__ neg,
                                                   float* __restrict__ out) {
    int rid  = blockIdx.x * 4 + (threadIdx.x >> 6);
    int lane = threadIdx.x & 63;
    if (rid >= NRID) return;
    int node = rid_to_node(rid, users, pos, neg);
    out[(size_t)rid * 256 + lane] = E[(size_t)node * DD + lane];
}

// ---- slice l+1: normalized current E of gathered rows (fp32) ----
__global__ __launch_bounds__(256) void k_outnorm(const float* __restrict__ E,
                                                 const int* __restrict__ users,
                                                 const int* __restrict__ pos,
                                                 const int* __restrict__ neg,
                                                 float* __restrict__ out,
                                                 int cbase) {
    int rid  = blockIdx.x * 4 + (threadIdx.x >> 6);
    int lane = threadIdx.x & 63;
    if (rid >= NRID) return;
    int node = rid_to_node(rid, users, pos, neg);
    float v = E[(size_t)node * DD + lane];
    float p2 = v * v;
    for (int m = 1; m < 64; m <<= 1) p2 += __shfl_xor(p2, m, 64);
    float nr = fmaxf(sqrtf(p2), 1e-12f);
    out[(size_t)rid * 256 + cbase + lane] = v / nr;
}

extern "C" void kernel_launch(void* const* d_in, const int* in_sizes, int n_in,
                              void* d_out, int out_size, void* d_ws, size_t ws_size,
                              hipStream_t stream) {
    const void* ue   = d_in[0];
    const void* ie   = d_in[1];
    const void* ev   = d_in[2];
    const void* W1   = d_in[3];
    const void* b1   = d_in[4];
    const void* W2   = d_in[5];
    const void* b2   = d_in[6];
    const int*  ei   = (const int*)d_in[7];
    const int*  usr  = (const int*)d_in[8];
    const int*  posi = (const int*)d_in[9];
    const int*  negi = (const int*)d_in[10];
    float*      out  = (float*)d_out;

    const int* rows = ei;
    const int* cols = ei + NNZC;

    // workspace carve — ~116 MB (Eb0 aliases binned: binned dead after phaseB;
    // Eb1 aliases the old LE slot: LE never goes to HBM in the fused design)
    char* w = (char*)d_ws;
    float*  E         = (float*)w;  w += (size_t)NN * DD * 4;    // 38.4 MB
    ushort_t* Eb1     = (ushort_t*)w; w += (size_t)NN * DD * 4;  // 19.2 MB used of 38.4
    int2*   binned    = (int2*)w;   w += (size_t)NNZC * 8;       // 19.2 MB
    ushort_t* Eb0     = (ushort_t*)binned;                       // alias (19.2 MB need)
    int2*   ep        = (int2*)w;   w += (size_t)NNZC * 8;       // 19.2 MB
    int*    row_ptr   = (int*)w;    w += 600320;                 // NN+1 ints padded
    int*    gbase     = (int*)w;    w += 1024;
    int*    gcursor   = (int*)w;    w += 1024;
    int*    bucket_cnt= (int*)w;    w += 1024;
    int*    flag      = (int*)w;    w += 256;
    ushort_t* Wfrag   = (ushort_t*)w; w += 49152;                // 3*4*4*64*8 bf16
    float*  bsum      = (float*)w;  w += 768;                    // 3*64 fp32

    k_sniffzb<<<1, 256, 0, stream>>>((const unsigned int*)ue, flag, bucket_cnt);
    k_wprep<<<97, 256, 0, stream>>>(W1, W2, b1, b2, flag, Wfrag, bsum);
    k_bhist<<<NABLK, 256, 0, stream>>>(rows, bucket_cnt);
    k_bscan<<<1, 256, 0, stream>>>(bucket_cnt, gbase, gcursor, row_ptr);
    k_phaseA<<<NABLK, 256, 0, stream>>>(rows, cols, ev, flag, gcursor, binned);
    k_phaseB<<<NBKT, 256, 0, stream>>>(gbase, binned, ep, row_ptr);
    k_init2<<<37500, 256, 0, stream>>>(ue, ie, flag, E, Eb0);   // after phaseB: binned dead

    k_outslice0<<<3072, 256, 0, stream>>>(E, usr, posi, negi, out);

    for (int l = 0; l < NLAYER; l++) {
        const ushort_t* ebi = (l & 1) ? Eb1 : Eb0;
        ushort_t*       ebo = (l & 1) ? Eb0 : Eb1;
        k_layer<<<NTILE, 256, 0, stream>>>(row_ptr, ep, ebi, E, ebo, Wfrag, bsum, l);
        k_outnorm<<<3072, 256, 0, stream>>>(E, usr, posi, negi, out, 64 * (l + 1));
    }
}